// Round 7
// baseline (143.525 us; speedup 1.0000x reference)
//
#include <hip/hip_runtime.h>
#include <hip/hip_bf16.h>

// B=32, N=128, K=16, F=D=256, H=4, DK=64.  out[4096,256] fp32.

typedef float f32x4 __attribute__((ext_vector_type(4)));
typedef __bf16 bf16x8 __attribute__((ext_vector_type(8)));

__device__ __forceinline__ unsigned short f2bf(float x) {
    unsigned int u = __float_as_uint(x);
    u += 0x7FFFu + ((u >> 16) & 1u);   // round-to-nearest-even
    return (unsigned short)(u >> 16);
}

// ---------------- kernel 0: [blocks 0..31] convert W_n to MFMA B-frag order
//                  [blocks 32..287] af = atom_feature @ W_a^T + b_a (16 atoms)
// W_n frag chunk c = ((wv*8 + kk)*4 + ni)*64 + lane holds
//   W[d = wv*64 + ni*16 + (lane&15)][f = kk*32 + (lane>>4)*8 .. +8)
__global__ __launch_bounds__(256) void prep(const float* __restrict__ atomf,
                                            const float* __restrict__ wa_f,
                                            const float* __restrict__ wn_f,
                                            unsigned short* __restrict__ own,
                                            const float* __restrict__ b_a,
                                            float* __restrict__ af) {
    const int blk = blockIdx.x;
    const int tid = threadIdx.x;
    if (blk < 32) {                       // ---- W_n convert+permute ----
        const int c = blk * 256 + tid;    // 0..8191 chunks of 8 bf16
        const int lane = c & 63, ni = (c >> 6) & 3, kk = (c >> 8) & 7, wv = c >> 11;
        const int d = wv * 64 + ni * 16 + (lane & 15);
        const int f = kk * 32 + (lane >> 4) * 8;
        const float* sp = wn_f + d * 256 + f;
        unsigned short h[8];
#pragma unroll
        for (int j = 0; j < 8; ++j) h[j] = f2bf(sp[j]);
        *(uint4*)(own + c * 8) = *(const uint4*)h;
        return;
    }
    // ---- atom projection, 16 atoms/block ----
    const int p = blk - 32;               // 0..255
    __shared__ char lds[16 * 512];
    const float4* src4 = (const float4*)(atomf + (size_t)p * 16 * 256);
    float4 v[4];
#pragma unroll
    for (int m = 0; m < 2; ++m) {
        v[2 * m]     = src4[tid * 2 + m * 512];
        v[2 * m + 1] = src4[tid * 2 + 1 + m * 512];
    }
#pragma unroll
    for (int m = 0; m < 2; ++m) {
        const int r = (tid >> 5) + 8 * m;            // row 0..15
        const int byt = (tid & 31) * 16;
        unsigned short h[8];
        h[0] = f2bf(v[2*m].x); h[1] = f2bf(v[2*m].y); h[2] = f2bf(v[2*m].z); h[3] = f2bf(v[2*m].w);
        h[4] = f2bf(v[2*m+1].x); h[5] = f2bf(v[2*m+1].y); h[6] = f2bf(v[2*m+1].z); h[7] = f2bf(v[2*m+1].w);
        *(uint4*)(lds + r * 512 + (byt ^ ((r & 7) << 4))) = *(const uint4*)h;
    }
    __syncthreads();
    const int lane = tid & 63, wv = tid >> 6, l15 = lane & 15, lg = lane >> 4;
    f32x4 acc[4];
#pragma unroll
    for (int ni = 0; ni < 4; ++ni)
#pragma unroll
        for (int j = 0; j < 4; ++j) acc[ni][j] = 0.f;
#pragma unroll
    for (int kk = 0; kk < 8; ++kk) {
        const int fb = (kk * 32 + lg * 8) * 2;
        const int r = l15;
        const bf16x8 afr = *(const bf16x8*)(lds + r * 512 + (fb ^ ((r & 7) << 4)));
#pragma unroll
        for (int ni = 0; ni < 4; ++ni) {
            // on-the-fly W_a fragment (fp32 -> bf16), no dependency on the convert blocks
            const float* wp = wa_f + (size_t)(wv * 64 + ni * 16 + l15) * 256 + kk * 32 + lg * 8;
            const float4 wx = *(const float4*)wp;
            const float4 wy = *(const float4*)(wp + 4);
            unsigned short hw[8];
            hw[0] = f2bf(wx.x); hw[1] = f2bf(wx.y); hw[2] = f2bf(wx.z); hw[3] = f2bf(wx.w);
            hw[4] = f2bf(wy.x); hw[5] = f2bf(wy.y); hw[6] = f2bf(wy.z); hw[7] = f2bf(wy.w);
            acc[ni] = __builtin_amdgcn_mfma_f32_16x16x32_bf16(afr, *(const bf16x8*)hw, acc[ni], 0, 0, 0);
        }
    }
#pragma unroll
    for (int ni = 0; ni < 4; ++ni) {
        const int d = wv * 64 + ni * 16 + l15;
        const float bav = b_a[d];
#pragma unroll
        for (int j = 0; j < 4; ++j)
            af[(size_t)(p * 16 + lg * 4 + j) * 256 + d] = acc[ni][j] + bav;
    }
}

// ---------------- kernel 1: fused neighbor proj + GATv2 attn + LN (4 atoms) ----
struct SmemG {
    char  a[64 * 512];        // bf16 A-tile, XOR-swizzled (32 KB)
    float af[4][256];         // projected atoms (+bias)
    float wal[64];
    float sm[4][16];
    float am[4][16];
    float red[4][4][2];       // [wave][atom][sum, sumsq]
};

__global__ __launch_bounds__(256, 3) void gat4(
        const float* __restrict__ nei, const float* __restrict__ af_buf,
        const unsigned short* __restrict__ wn_p, const float* __restrict__ b_n,
        const float* __restrict__ smask, const float* __restrict__ amask,
        const float* __restrict__ w_align, const float* __restrict__ b_align,
        const float* __restrict__ gamma, const float* __restrict__ beta,
        float* __restrict__ out) {
    __shared__ SmemG s;
    const int tid = threadIdx.x;
    const int p = blockIdx.x;            // atoms 4p..4p+3, neighbor rows 64p..64p+63

    // small loads issued first
    if (tid < 64) {
        s.wal[tid] = w_align[tid];
        ((float*)s.sm)[tid] = smask[p * 64 + tid];
        ((float*)s.am)[tid] = amask[p * 64 + tid];
    }
#pragma unroll
    for (int a2 = 0; a2 < 4; ++a2)
        s.af[a2][tid] = af_buf[(size_t)p * 1024 + a2 * 256 + tid];

    // ---- stage 64 neighbor rows: ALL 16 loads in flight, then pack+write b128
    const float4* src4 = (const float4*)(nei + (size_t)p * 64 * 256);
    float4 v[16];
#pragma unroll
    for (int m = 0; m < 8; ++m) {
        v[2 * m]     = src4[tid * 2 + m * 512];
        v[2 * m + 1] = src4[tid * 2 + 1 + m * 512];
    }
#pragma unroll
    for (int m = 0; m < 8; ++m) {
        const int r = (tid >> 5) + 8 * m;            // row 0..63, one 16B chunk/lane
        const int byt = (tid & 31) * 16;
        unsigned short h[8];
        h[0] = f2bf(v[2*m].x); h[1] = f2bf(v[2*m].y); h[2] = f2bf(v[2*m].z); h[3] = f2bf(v[2*m].w);
        h[4] = f2bf(v[2*m+1].x); h[5] = f2bf(v[2*m+1].y); h[6] = f2bf(v[2*m+1].z); h[7] = f2bf(v[2*m+1].w);
        *(uint4*)(s.a + r * 512 + (byt ^ ((r & 7) << 4))) = *(const uint4*)h;
    }
    __syncthreads();

    const int lane = tid & 63, wv = tid >> 6, l15 = lane & 15, lg = lane >> 4;

    f32x4 acc[4][4];                     // [atom(M-tile)][ni]
#pragma unroll
    for (int a = 0; a < 4; ++a)
#pragma unroll
        for (int ni = 0; ni < 4; ++ni)
#pragma unroll
            for (int j = 0; j < 4; ++j) acc[a][ni][j] = 0.f;

    // ---- K-loop: B-frags double-buffered in registers, pinned live ----
    const unsigned short* w = wn_p + wv * 16384 + lane * 8;
    bf16x8 cur[4], nxt[4];
#pragma unroll
    for (int ni = 0; ni < 4; ++ni) cur[ni] = *(const bf16x8*)(w + ni * 512);
#pragma unroll
    for (int kk = 0; kk < 8; ++kk) {
        if (kk < 7) {
#pragma unroll
            for (int ni = 0; ni < 4; ++ni)
                nxt[ni] = *(const bf16x8*)(w + (kk + 1) * 2048 + ni * 512);
        }
        const int fb = (kk * 32 + lg * 8) * 2;
        bf16x8 afr[4];
#pragma unroll
        for (int a = 0; a < 4; ++a) {
            const int r = a * 16 + l15;
            afr[a] = *(const bf16x8*)(s.a + r * 512 + (fb ^ ((r & 7) << 4)));
        }
#pragma unroll
        for (int ni = 0; ni < 4; ++ni)
#pragma unroll
            for (int a = 0; a < 4; ++a)
                acc[a][ni] = __builtin_amdgcn_mfma_f32_16x16x32_bf16(afr[a], cur[ni], acc[a][ni], 0, 0, 0);
        if (kk < 7) {
            // pin the prefetched frags live here: forbids sinking the loads
            asm volatile("" :: "v"(nxt[0]), "v"(nxt[1]), "v"(nxt[2]), "v"(nxt[3]));
#pragma unroll
            for (int ni = 0; ni < 4; ++ni) cur[ni] = nxt[ni];
        }
    }

    // ---- register epilogue. lane holds nf[atom a][k=lg*4+j][d=wv*64+ni*16+l15]
    float bn4[4], wl4[4];
#pragma unroll
    for (int ni = 0; ni < 4; ++ni) {
        bn4[ni] = b_n[wv * 64 + ni * 16 + l15];
        wl4[ni] = s.wal[ni * 16 + l15];        // w_align is per-head-relative (DK=64)
    }
#pragma unroll
    for (int a = 0; a < 4; ++a)
#pragma unroll
        for (int ni = 0; ni < 4; ++ni)
#pragma unroll
            for (int j = 0; j < 4; ++j) acc[a][ni][j] += bn4[ni];   // nf += b_n

    const float bal = b_align[0];
    float ctx[4][4];
#pragma unroll
    for (int a = 0; a < 4; ++a) {
        float afd[4];
#pragma unroll
        for (int ni = 0; ni < 4; ++ni)
            afd[ni] = s.af[a][wv * 64 + ni * 16 + l15];   // head offset wv*64
        float sj[4];
#pragma unroll
        for (int j = 0; j < 4; ++j) {
            float t = 0.f;
#pragma unroll
            for (int ni = 0; ni < 4; ++ni) {
                float z = afd[ni] + acc[a][ni][j];
                z = fmaxf(z, 0.2f * z);                 // LeakyReLU(0.2)
                t = fmaf(z, wl4[ni], t);
            }
            sj[j] = t;
        }
#pragma unroll
        for (int j = 0; j < 4; ++j) {
#pragma unroll
            for (int o = 1; o < 16; o <<= 1) sj[j] += __shfl_xor(sj[j], o);
            sj[j] += bal + s.sm[a][lg * 4 + j];
        }
        float m = fmaxf(fmaxf(sj[0], sj[1]), fmaxf(sj[2], sj[3]));
        m = fmaxf(m, __shfl_xor(m, 16));
        m = fmaxf(m, __shfl_xor(m, 32));
        float e[4], sum = 0.f;
#pragma unroll
        for (int j = 0; j < 4; ++j) { e[j] = __expf(sj[j] - m); sum += e[j]; }
        sum += __shfl_xor(sum, 16);
        sum += __shfl_xor(sum, 32);
        const float inv = 1.f / sum;
        float aw[4];
#pragma unroll
        for (int j = 0; j < 4; ++j) aw[j] = e[j] * inv * s.am[a][lg * 4 + j];
#pragma unroll
        for (int ni = 0; ni < 4; ++ni) {
            float c = 0.f;
#pragma unroll
            for (int j = 0; j < 4; ++j) c = fmaf(aw[j], acc[a][ni][j], c);
            c += __shfl_xor(c, 16);
            c += __shfl_xor(c, 32);
            ctx[a][ni] = c;
        }
        float t = 0.f, q = 0.f;
#pragma unroll
        for (int ni = 0; ni < 4; ++ni) { t += ctx[a][ni]; q = fmaf(ctx[a][ni], ctx[a][ni], q); }
#pragma unroll
        for (int o = 1; o < 16; o <<= 1) { t += __shfl_xor(t, o); q += __shfl_xor(q, o); }
        if (lane == 0) { s.red[wv][a][0] = t; s.red[wv][a][1] = q; }
    }
    __syncthreads();

    const float g = gamma[wv * 64 + lane];
    const float be = beta[wv * 64 + lane];
#pragma unroll
    for (int a = 0; a < 4; ++a) {
        float ts = 0.f, tq = 0.f;
#pragma unroll
        for (int q2 = 0; q2 < 4; ++q2) { ts += s.red[q2][a][0]; tq += s.red[q2][a][1]; }
        const float mu = ts * (1.f / 256.f);
        float var = tq * (1.f / 256.f) - mu * mu;
        var = fmaxf(var, 0.f);
        const float rs = rsqrtf(var + 1e-5f);
        const float cv = (lg == 0) ? ctx[a][0] : (lg == 1) ? ctx[a][1]
                        : (lg == 2) ? ctx[a][2] : ctx[a][3];
        out[(size_t)(p * 4 + a) * 256 + wv * 64 + lane] = (cv - mu) * rs * g + be;
    }
}

extern "C" void kernel_launch(void* const* d_in, const int* in_sizes, int n_in,
                              void* d_out, int out_size, void* d_ws, size_t ws_size,
                              hipStream_t stream) {
    const float* atomf = (const float*)d_in[0];
    const float* nei   = (const float*)d_in[1];
    const float* smask = (const float*)d_in[2];
    const float* amask = (const float*)d_in[3];
    const float* Wa    = (const float*)d_in[4];
    const float* ba    = (const float*)d_in[5];
    const float* Wn    = (const float*)d_in[6];
    const float* bn    = (const float*)d_in[7];
    const float* wal   = (const float*)d_in[8];
    const float* bal   = (const float*)d_in[9];
    const float* gam   = (const float*)d_in[10];
    const float* bet   = (const float*)d_in[11];
    float* out = (float*)d_out;

    char* ws = (char*)d_ws;
    float*          af_buf = (float*)ws;                               // 4 MiB
    unsigned short* wn_bf  = (unsigned short*)(ws + 4194304);          // 128 KiB

    hipLaunchKernelGGL(prep, dim3(288), dim3(256), 0, stream,
                       atomf, Wa, Wn, wn_bf, ba, af_buf);
    hipLaunchKernelGGL(gat4, dim3(1024), dim3(256), 0, stream,
                       nei, af_buf, wn_bf, bn, smask, amask,
                       wal, bal, gam, bet, out);
}

// Round 8
// 137.963 us; speedup vs baseline: 1.0403x; 1.0403x over previous
//
#include <hip/hip_runtime.h>
#include <hip/hip_bf16.h>

// B=32, N=128, K=16, F=D=256, H=4, DK=64.  out[4096,256] fp32.

typedef float f32x4 __attribute__((ext_vector_type(4)));
typedef __bf16 bf16x8 __attribute__((ext_vector_type(8)));

__device__ __forceinline__ unsigned short f2bf(float x) {
    unsigned int u = __float_as_uint(x);
    u += 0x7FFFu + ((u >> 16) & 1u);   // round-to-nearest-even
    return (unsigned short)(u >> 16);
}

// ---------------- kernel 0: convert + permute W_a, W_n to MFMA B-frag order ---
// chunk c = ((wv*8 + kk)*4 + ni)*64 + lane holds
//   W[d = wv*64 + ni*16 + (lane&15)][f = kk*32 + (lane>>4)*8 .. +8)
__global__ __launch_bounds__(256) void conv_w(const float* __restrict__ wa,
                                              const float* __restrict__ wn,
                                              unsigned short* __restrict__ owa,
                                              unsigned short* __restrict__ own) {
    const int g = blockIdx.x * 256 + threadIdx.x;     // 0..16383
    const float* src = (g & 8192) ? wn : wa;
    unsigned short* dst = (g & 8192) ? own : owa;
    const int c = g & 8191;
    const int lane = c & 63, ni = (c >> 6) & 3, kk = (c >> 8) & 7, wv = c >> 11;
    const int d = wv * 64 + ni * 16 + (lane & 15);
    const int f = kk * 32 + (lane >> 4) * 8;
    const float* sp = src + d * 256 + f;
    unsigned short h[8];
#pragma unroll
    for (int j = 0; j < 8; ++j) h[j] = f2bf(sp[j]);
    *(uint4*)(dst + c * 8) = *(const uint4*)h;
}

// ---------------- kernel 1: ONE fused kernel: proj(atom+nei) + attn + LN ------
// 4 atoms/block. A-tile: rows 0-63 neighbors, rows 64-67 atoms (5th M-tile).
struct SmemG {
    char  a[68 * 512];        // bf16 A-tile, XOR-swizzled (34 KB)
    float sm[4][16];
    float am[4][16];
    float red[4][4][2];       // [wave][atom][sum, sumsq]
};

__global__ __launch_bounds__(256, 3) void gat_one(
        const float* __restrict__ atomf, const float* __restrict__ nei,
        const unsigned short* __restrict__ wn_p, const unsigned short* __restrict__ wa_p,
        const float* __restrict__ b_n, const float* __restrict__ b_a,
        const float* __restrict__ smask, const float* __restrict__ amask,
        const float* __restrict__ w_align, const float* __restrict__ b_align,
        const float* __restrict__ gamma, const float* __restrict__ beta,
        float* __restrict__ out) {
    __shared__ SmemG s;
    const int tid = threadIdx.x;
    const int p = blockIdx.x;            // atoms 4p..4p+3, neighbor rows 64p..64p+63

    if (tid < 64) {
        ((float*)s.sm)[tid] = smask[p * 64 + tid];
        ((float*)s.am)[tid] = amask[p * 64 + tid];
    }

    // ---- stage 64 neighbor rows (2 batches of 8 loads) + 4 atom rows ----
    const float4* src4 = (const float4*)(nei + (size_t)p * 64 * 256);
#pragma unroll
    for (int half = 0; half < 2; ++half) {
        float4 v[8];
#pragma unroll
        for (int m = 0; m < 4; ++m) {
            v[2 * m]     = src4[tid * 2 + (half * 4 + m) * 512];
            v[2 * m + 1] = src4[tid * 2 + 1 + (half * 4 + m) * 512];
        }
#pragma unroll
        for (int m = 0; m < 4; ++m) {
            const int r = (tid >> 5) + 8 * (half * 4 + m);   // row 0..63
            const int byt = (tid & 31) * 16;
            unsigned short h[8];
            h[0] = f2bf(v[2*m].x); h[1] = f2bf(v[2*m].y); h[2] = f2bf(v[2*m].z); h[3] = f2bf(v[2*m].w);
            h[4] = f2bf(v[2*m+1].x); h[5] = f2bf(v[2*m+1].y); h[6] = f2bf(v[2*m+1].z); h[7] = f2bf(v[2*m+1].w);
            *(uint4*)(s.a + r * 512 + (byt ^ ((r & 7) << 4))) = *(const uint4*)h;
        }
    }
    {   // atom rows 64..67: one float4 (16B fp32 -> 8B bf16) per thread
        const int at = tid >> 6, cc = tid & 63;
        const float4 v = *(const float4*)(atomf + (size_t)(p * 4 + at) * 256 + cc * 4);
        const int r = 64 + at;
        ushort4 h;
        h.x = f2bf(v.x); h.y = f2bf(v.y); h.z = f2bf(v.z); h.w = f2bf(v.w);
        *(ushort4*)(s.a + r * 512 + ((cc * 8) ^ ((r & 7) << 4))) = h;
    }
    __syncthreads();

    const int lane = tid & 63, wv = tid >> 6, l15 = lane & 15, lg = lane >> 4;

    f32x4 acc[4][4];                     // neighbor tiles [atom][ni]
    f32x4 accA[4];                       // atom tile [ni]
#pragma unroll
    for (int a = 0; a < 4; ++a)
#pragma unroll
        for (int ni = 0; ni < 4; ++ni)
#pragma unroll
            for (int j = 0; j < 4; ++j) acc[a][ni][j] = 0.f;
#pragma unroll
    for (int ni = 0; ni < 4; ++ni)
#pragma unroll
        for (int j = 0; j < 4; ++j) accA[ni][j] = 0.f;

    // ---- K-loop: W_n frags double-buffered+pinned; W_a frags in-loop (L2-hot)
    const unsigned short* wn_wv = wn_p + wv * 16384 + lane * 8;
    const unsigned short* wa_wv = wa_p + wv * 16384 + lane * 8;
    bf16x8 cn[4], nx[4];
#pragma unroll
    for (int ni = 0; ni < 4; ++ni) cn[ni] = *(const bf16x8*)(wn_wv + ni * 512);
#pragma unroll
    for (int kk = 0; kk < 8; ++kk) {
        if (kk < 7) {
#pragma unroll
            for (int ni = 0; ni < 4; ++ni)
                nx[ni] = *(const bf16x8*)(wn_wv + (kk + 1) * 2048 + ni * 512);
        }
        const int fb = (kk * 32 + lg * 8) * 2;
        bf16x8 afr[5];
#pragma unroll
        for (int a = 0; a < 4; ++a) {
            const int r = a * 16 + l15;
            afr[a] = *(const bf16x8*)(s.a + r * 512 + (fb ^ ((r & 7) << 4)));
        }
        {   // atom tile: only rows 0-3 of the tile are real; duplicate for l15>=4
            const int r = 64 + (l15 & 3);
            afr[4] = *(const bf16x8*)(s.a + r * 512 + (fb ^ ((r & 7) << 4)));
        }
#pragma unroll
        for (int ni = 0; ni < 4; ++ni) {
            const bf16x8 ca = *(const bf16x8*)(wa_wv + kk * 2048 + ni * 512);
#pragma unroll
            for (int a = 0; a < 4; ++a)
                acc[a][ni] = __builtin_amdgcn_mfma_f32_16x16x32_bf16(afr[a], cn[ni], acc[a][ni], 0, 0, 0);
            accA[ni] = __builtin_amdgcn_mfma_f32_16x16x32_bf16(afr[4], ca, accA[ni], 0, 0, 0);
        }
        if (kk < 7) {
            asm volatile("" :: "v"(nx[0]), "v"(nx[1]), "v"(nx[2]), "v"(nx[3]));
#pragma unroll
            for (int ni = 0; ni < 4; ++ni) cn[ni] = nx[ni];
        }
    }

    // ---- register epilogue. lane holds nf[a][k=lg*4+j][d=wv*64+ni*16+l15];
    //      af[atom j][d] sits in accA[ni][j] of lanes 0-15 (lg==0).
    float bn4[4], ba4[4], wl4[4];
#pragma unroll
    for (int ni = 0; ni < 4; ++ni) {
        const int dd = wv * 64 + ni * 16 + l15;
        bn4[ni] = b_n[dd];
        ba4[ni] = b_a[dd];
        wl4[ni] = w_align[ni * 16 + l15];      // per-head-relative (DK=64)
    }
#pragma unroll
    for (int a = 0; a < 4; ++a)
#pragma unroll
        for (int ni = 0; ni < 4; ++ni)
#pragma unroll
            for (int j = 0; j < 4; ++j) acc[a][ni][j] += bn4[ni];   // nf += b_n

    const float bal = b_align[0];
    float ctx[4][4];
#pragma unroll
    for (int a = 0; a < 4; ++a) {
        float afd[4];
#pragma unroll
        for (int ni = 0; ni < 4; ++ni)
            afd[ni] = __shfl(accA[ni][a], l15) + ba4[ni];   // bcast from lane l15
        float sj[4];
#pragma unroll
        for (int j = 0; j < 4; ++j) {
            float t = 0.f;
#pragma unroll
            for (int ni = 0; ni < 4; ++ni) {
                float z = afd[ni] + acc[a][ni][j];
                z = fmaxf(z, 0.2f * z);                 // LeakyReLU(0.2)
                t = fmaf(z, wl4[ni], t);
            }
            sj[j] = t;
        }
#pragma unroll
        for (int j = 0; j < 4; ++j) {
#pragma unroll
            for (int o = 1; o < 16; o <<= 1) sj[j] += __shfl_xor(sj[j], o);
            sj[j] += bal + s.sm[a][lg * 4 + j];
        }
        float m = fmaxf(fmaxf(sj[0], sj[1]), fmaxf(sj[2], sj[3]));
        m = fmaxf(m, __shfl_xor(m, 16));
        m = fmaxf(m, __shfl_xor(m, 32));
        float e[4], sum = 0.f;
#pragma unroll
        for (int j = 0; j < 4; ++j) { e[j] = __expf(sj[j] - m); sum += e[j]; }
        sum += __shfl_xor(sum, 16);
        sum += __shfl_xor(sum, 32);
        const float inv = 1.f / sum;
        float aw[4];
#pragma unroll
        for (int j = 0; j < 4; ++j) aw[j] = e[j] * inv * s.am[a][lg * 4 + j];
#pragma unroll
        for (int ni = 0; ni < 4; ++ni) {
            float c = 0.f;
#pragma unroll
            for (int j = 0; j < 4; ++j) c = fmaf(aw[j], acc[a][ni][j], c);
            c += __shfl_xor(c, 16);
            c += __shfl_xor(c, 32);
            ctx[a][ni] = c;
        }
        float t = 0.f, q = 0.f;
#pragma unroll
        for (int ni = 0; ni < 4; ++ni) { t += ctx[a][ni]; q = fmaf(ctx[a][ni], ctx[a][ni], q); }
#pragma unroll
        for (int o = 1; o < 16; o <<= 1) { t += __shfl_xor(t, o); q += __shfl_xor(q, o); }
        if (lane == 0) { s.red[wv][a][0] = t; s.red[wv][a][1] = q; }
    }
    __syncthreads();

    const float g = gamma[wv * 64 + lane];
    const float be = beta[wv * 64 + lane];
#pragma unroll
    for (int a = 0; a < 4; ++a) {
        float ts = 0.f, tq = 0.f;
#pragma unroll
        for (int q2 = 0; q2 < 4; ++q2) { ts += s.red[q2][a][0]; tq += s.red[q2][a][1]; }
        const float mu = ts * (1.f / 256.f);
        float var = tq * (1.f / 256.f) - mu * mu;
        var = fmaxf(var, 0.f);
        const float rs = rsqrtf(var + 1e-5f);
        const float cv = (lg == 0) ? ctx[a][0] : (lg == 1) ? ctx[a][1]
                        : (lg == 2) ? ctx[a][2] : ctx[a][3];
        out[(size_t)(p * 4 + a) * 256 + wv * 64 + lane] = (cv - mu) * rs * g + be;
    }
}

extern "C" void kernel_launch(void* const* d_in, const int* in_sizes, int n_in,
                              void* d_out, int out_size, void* d_ws, size_t ws_size,
                              hipStream_t stream) {
    const float* atomf = (const float*)d_in[0];
    const float* nei   = (const float*)d_in[1];
    const float* smask = (const float*)d_in[2];
    const float* amask = (const float*)d_in[3];
    const float* Wa    = (const float*)d_in[4];
    const float* ba    = (const float*)d_in[5];
    const float* Wn    = (const float*)d_in[6];
    const float* bn    = (const float*)d_in[7];
    const float* wal   = (const float*)d_in[8];
    const float* bal   = (const float*)d_in[9];
    const float* gam   = (const float*)d_in[10];
    const float* bet   = (const float*)d_in[11];
    float* out = (float*)d_out;

    char* ws = (char*)d_ws;
    unsigned short* wa_bf = (unsigned short*)ws;             // 128 KiB
    unsigned short* wn_bf = (unsigned short*)(ws + 131072);  // 128 KiB

    hipLaunchKernelGGL(conv_w, dim3(64), dim3(256), 0, stream,
                       Wa, Wn, wa_bf, wn_bf);
    hipLaunchKernelGGL(gat_one, dim3(1024), dim3(256), 0, stream,
                       atomf, nei, wn_bf, wa_bf, bn, ba, smask, amask,
                       wal, bal, gam, bet, out);
}